// Round 5
// baseline (244.142 us; speedup 1.0000x reference)
//
#include <hip/hip_runtime.h>
#include <math.h>

#define BN 4096
#define DIM 256
#define D4 (DIM/4)        // 64 float4 per row
#define MI 8              // anchors per workgroup (fallback k_main)
#define MT 16             // anchors per workgroup (transpose-path k_main_t)
#define MARGINF 0.3f
#define EPSF 1e-6f
#define SCAP 96           // staged class-member rows in k_pos (LDS)

typedef float v2f __attribute__((ext_vector_type(2)));

// Guaranteed packed FMA: acc{lo,hi} += splat(A.lo or A.hi) * b{lo,hi}
// A operand is an SGPR pair; op_sel broadcasts one 32-bit half to both lanes.
#define PKFMA_LO(acc, a2, b2) \
  asm("v_pk_fma_f32 %0, %1, %2, %0 op_sel:[0,0,0] op_sel_hi:[0,1,1]" \
      : "+v"(acc) : "s"(a2), "v"(b2))
#define PKFMA_HI(acc, a2, b2) \
  asm("v_pk_fma_f32 %0, %1, %2, %0 op_sel:[1,0,0] op_sel_hi:[1,1,1]" \
      : "+v"(acc) : "s"(a2), "v"(b2))

__device__ __forceinline__ float fma4(float4 a, float4 b, float c){
  return fmaf(a.x,b.x, fmaf(a.y,b.y, fmaf(a.z,b.z, fmaf(a.w,b.w, c))));
}

// ---------------- kernel 0: per-row squared norms ----------------
__global__ __launch_bounds__(256) void k_sq(const float* __restrict__ E, float* __restrict__ sq){
  int i = blockIdx.x*256 + threadIdx.x;
  if (i >= BN) return;
  const float4* r = (const float4*)E + (size_t)i*D4;
  float a0=0.f,a1=0.f,a2=0.f,a3=0.f;
  #pragma unroll
  for (int q=0;q<D4;q+=4){
    a0 = fma4(r[q],r[q],a0);   a1 = fma4(r[q+1],r[q+1],a1);
    a2 = fma4(r[q+2],r[q+2],a2); a3 = fma4(r[q+3],r[q+3],a3);
  }
  sq[i] = (a0+a1)+(a2+a3);
}

// ---------------- kernel 0b: transpose E (4096x256) -> ET (256x4096) ----------------
__global__ __launch_bounds__(256) void k_tr(const float* __restrict__ E, float* __restrict__ ET){
  __shared__ float tile[64][65];
  int t = threadIdx.x;
  int jt = blockIdx.x & 63, kt = blockIdx.x >> 6;   // 64 j-tiles x 4 k-tiles
  int j0 = jt<<6, k0 = kt<<6;
  const float4* E4 = (const float4*)E;
  int rr = t>>4, cc = t&15;
  #pragma unroll
  for (int ps=0; ps<4; ps++){
    int r = rr + ps*16;
    float4 v = E4[(size_t)(j0+r)*D4 + (k0>>2) + cc];
    tile[r][cc*4+0]=v.x; tile[r][cc*4+1]=v.y; tile[r][cc*4+2]=v.z; tile[r][cc*4+3]=v.w;
  }
  __syncthreads();
  float4* ET4 = (float4*)ET;
  #pragma unroll
  for (int ps=0; ps<4; ps++){
    int kk = rr + ps*16;
    float4 v;
    v.x = tile[cc*4+0][kk]; v.y = tile[cc*4+1][kk];
    v.z = tile[cc*4+2][kk]; v.w = tile[cc*4+3][kk];
    ET4[(size_t)(k0+kk)*1024 + (j0>>2) + cc] = v;
  }
}

// ------ kernel 1: per-class hardest positive (ap_dist, hp_idx, any_pos) ------
// v4: 4 barriers total. 2-phase count/place compaction; per-wave-independent
// mi loop (no cross-wave reduction, no barriers inside).
__global__ __launch_bounds__(256) void k_pos(const float* __restrict__ E, const int* __restrict__ labels,
                       const float* __restrict__ sq, float* __restrict__ apw,
                       int* __restrict__ hpw, int* __restrict__ anypw){
  __shared__ int members[1024];
  __shared__ float4 mem4[SCAP*65];      // ~99.8 KB staged member rows
  __shared__ int cnts[16][4];
  __shared__ int offs[16][4];
  __shared__ int cntS;
  int t = threadIdx.x, lane = t&63, w = t>>6;
  int c = blockIdx.x >> 2, split = blockIdx.x & 3;
  // phase A: per-(chunk,wave) match counts
  for (int ch=0; ch<16; ch++){
    bool m = (labels[ch*256 + t] == c);
    unsigned long long mask = __ballot(m);
    if (lane==0) cnts[ch][w] = __popcll(mask);
  }
  __syncthreads();
  if (t==0){
    int run=0;
    for (int ch=0; ch<16; ch++)
      for (int q=0;q<4;q++){ offs[ch][q]=run; run+=cnts[ch][q]; }
    cntS = run;
  }
  __syncthreads();
  int cnt = cntS; if (cnt>1024) cnt=1024;
  // phase B: ordered placement (idx ascending globally)
  for (int ch=0; ch<16; ch++){
    int idx = ch*256 + t;
    bool m = (labels[idx] == c);
    unsigned long long mask = __ballot(m);
    int my = __popcll(mask & ((1ull<<lane)-1ull));
    int pos = offs[ch][w] + my;
    if (m && pos < 1024) members[pos] = idx;
  }
  int S = (cnt < SCAP) ? cnt : SCAP;
  int anyp = (cnt >= 2) ? 1 : 0;
  __syncthreads();
  const float4* E4 = (const float4*)E;
  for (int idx=t; idx<S*64; idx+=256){
    int row = idx>>6, f = idx&63;
    mem4[row*65 + f] = E4[(size_t)members[row]*D4 + f];
  }
  __syncthreads();
  // per-wave independent mi loop; lanes: p = k-split quad, cand = candidate
  int esplit = split*4 + w;             // 0..15
  int p = lane&3, cand = lane>>2;
  int passes = (cnt+15)>>4;
  for (int mi=esplit; mi<cnt; mi+=16){
    int i = members[mi];
    float sqi = sq[i];
    // anchor k-slice into registers (dims p+4m)
    float4 ai4[16];
    if (mi < S){
      #pragma unroll
      for (int m=0;m<16;m++) ai4[m] = mem4[mi*65 + p + 4*m];
    } else {
      #pragma unroll
      for (int m=0;m<16;m++) ai4[m] = E4[(size_t)i*D4 + p + 4*m];
    }
    float bv = -INFINITY; int bj = 0x7fffffff;
    for (int ps=0; ps<passes; ps++){
      int mj = ps*16 + cand;
      if (mj < cnt && mj != mi){
        int j = members[mj];
        float a0v=0.f, a1v=0.f;
        if (mj < S){
          const float4* rj = mem4 + mj*65 + p;
          #pragma unroll
          for (int m=0;m<16;m+=2){ a0v=fma4(ai4[m],rj[4*m],a0v); a1v=fma4(ai4[m+1],rj[4*(m+1)],a1v); }
        } else {
          const float4* rj = E4 + (size_t)j*D4 + p;
          #pragma unroll
          for (int m=0;m<16;m+=2){ a0v=fma4(ai4[m],rj[4*m],a0v); a1v=fma4(ai4[m+1],rj[4*(m+1)],a1v); }
        }
        float acc = a0v+a1v;
        acc += __shfl_xor(acc,1); acc += __shfl_xor(acc,2);   // quad partial sum
        float d = sqrtf(fmaxf(sqi + sq[j] - 2.0f*acc, 0.0f));
        // ascending mj across passes => ascending j; strict > keeps first max
        if (p==0){ if (d > bv || (d==bv && j<bj)){ bv=d; bj=j; } }
      }
    }
    #pragma unroll
    for (int off=32; off; off>>=1){
      float v2=__shfl_xor(bv,off); int j2=__shfl_xor(bj,off);
      if (v2>bv || (v2==bv && j2<bj)){ bv=v2; bj=j2; }
    }
    if (lane==0){
      int J = (bj==0x7fffffff) ? 0 : bj;
      apw[i]=bv; hpw[i]=J; anypw[i]=anyp;
    }
  }
}

// ------ kernel 2 (transpose path): full-dot-per-lane GEMM + mining + loss ------
// v5: inner product via explicit v_pk_fma_f32 (inline asm, SGPR-A broadcast
// through op_sel). B col-pairs are natural VGPR pairs from dwordx4 ET loads.
// 2x-unrolled kb loop keeps 8 B-loads in flight. No LDS in the k-loop.
__global__ __launch_bounds__(512,2) void k_main_t(const float* __restrict__ E, const float* __restrict__ ET,
     const int* __restrict__ labels, const float* __restrict__ sq, const float* __restrict__ apw,
     const int* __restrict__ hpw, const int* __restrict__ anypw, float* __restrict__ partials){
  __shared__ float redv[8][MT]; __shared__ int redj[8][MT]; __shared__ int redsm[8][MT];
  __shared__ int finNeg[MT]; __shared__ int finVal[MT];
  __shared__ float redp[4], redn[4];
  int t=threadIdx.x, l=t&63, w=t>>6;
  int a0 = blockIdx.x * MT;
  const float4* E4  = (const float4*)E;
  const float4* ET4 = (const float4*)ET;

  float mnv[MT]; int mnj[MT]; int smj[MT];
  #pragma unroll
  for (int a=0;a<MT;a++){ mnv[a]=INFINITY; mnj[a]=0; smj[a]=0x7fffffff; }

  for (int g=0; g<2; g++){
    int it = w + 8*g;                    // this wave's column group
    int colb = it*256 + 4*l;             // lane's 4 consecutive cols
    v2f acc[MT][2];
    #pragma unroll
    for (int a=0;a<MT;a++){ acc[a][0]=(v2f)(0.0f); acc[a][1]=(v2f)(0.0f); }
    const float4* bp = ET4 + it*64 + l;  // + k*1024
    for (int kb=0; kb<64; kb+=2){
      // 8 B-lines in flight (dims 4kb .. 4kb+7), each 64 lanes x 16B coalesced
      float4 e0 = bp[(4*kb+0)*1024];
      float4 e1 = bp[(4*kb+1)*1024];
      float4 e2 = bp[(4*kb+2)*1024];
      float4 e3 = bp[(4*kb+3)*1024];
      float4 f0 = bp[(4*kb+4)*1024];
      float4 f1 = bp[(4*kb+5)*1024];
      float4 f2 = bp[(4*kb+6)*1024];
      float4 f3 = bp[(4*kb+7)*1024];
      v2f e0l={e0.x,e0.y}, e0h={e0.z,e0.w};
      v2f e1l={e1.x,e1.y}, e1h={e1.z,e1.w};
      v2f e2l={e2.x,e2.y}, e2h={e2.z,e2.w};
      v2f e3l={e3.x,e3.y}, e3h={e3.z,e3.w};
      #pragma unroll
      for (int a=0;a<MT;a++){
        float4 av = E4[(a0+a)*D4 + kb];          // uniform -> s_load_dwordx4
        v2f a01 = {av.x, av.y}, a23 = {av.z, av.w};
        PKFMA_LO(acc[a][0], a01, e0l); PKFMA_LO(acc[a][1], a01, e0h);
        PKFMA_HI(acc[a][0], a01, e1l); PKFMA_HI(acc[a][1], a01, e1h);
        PKFMA_LO(acc[a][0], a23, e2l); PKFMA_LO(acc[a][1], a23, e2h);
        PKFMA_HI(acc[a][0], a23, e3l); PKFMA_HI(acc[a][1], a23, e3h);
      }
      v2f f0l={f0.x,f0.y}, f0h={f0.z,f0.w};
      v2f f1l={f1.x,f1.y}, f1h={f1.z,f1.w};
      v2f f2l={f2.x,f2.y}, f2h={f2.z,f2.w};
      v2f f3l={f3.x,f3.y}, f3h={f3.z,f3.w};
      #pragma unroll
      for (int a=0;a<MT;a++){
        float4 aw = E4[(a0+a)*D4 + kb+1];        // uniform -> s_load_dwordx4
        v2f a01 = {aw.x, aw.y}, a23 = {aw.z, aw.w};
        PKFMA_LO(acc[a][0], a01, f0l); PKFMA_LO(acc[a][1], a01, f0h);
        PKFMA_HI(acc[a][0], a01, f1l); PKFMA_HI(acc[a][1], a01, f1h);
        PKFMA_LO(acc[a][0], a23, f2l); PKFMA_LO(acc[a][1], a23, f2h);
        PKFMA_HI(acc[a][0], a23, f3l); PKFMA_HI(acc[a][1], a23, f3h);
      }
    }
    // selection epilogue: 4 cols per lane, j ascending (within lane and across g)
    int4   lj4 = *(const int4*  )(labels + colb);
    float4 sj4 = *(const float4*)(sq + colb);
    float sjv[4] = {sj4.x,sj4.y,sj4.z,sj4.w};
    int   ljv[4] = {lj4.x,lj4.y,lj4.z,lj4.w};
    #pragma unroll
    for (int a=0;a<MT;a++){
      float sqa = sq[a0+a]; float apv = apw[a0+a]; int labi = labels[a0+a];
      float dot[4] = {acc[a][0].x, acc[a][0].y, acc[a][1].x, acc[a][1].y};
      #pragma unroll
      for (int c2=0;c2<4;c2++){
        int j = colb + c2;
        float d = sqrtf(fmaxf(sqa + sjv[c2] - 2.0f*dot[c2], 0.0f));
        if (ljv[c2] != labi){
          if (d < mnv[a]){ mnv[a]=d; mnj[a]=j; }             // strict <: first min
          if (d > apv && d < apv+MARGINF && j < smj[a]) smj[a]=j;
        }
      }
    }
  }

  // wave reduction then 8-wave LDS reduction (first-index tie-breaks on j)
  #pragma unroll
  for (int a=0;a<MT;a++){
    float v=mnv[a]; int j=mnj[a]; int sm=smj[a];
    #pragma unroll
    for (int off=32; off; off>>=1){
      float v2=__shfl_xor(v,off); int j2=__shfl_xor(j,off); int s2=__shfl_xor(sm,off);
      if (v2<v || (v2==v && j2<j)){ v=v2; j=j2; }
      sm = (s2<sm)?s2:sm;
    }
    if (l==0){ redv[w][a]=v; redj[w][a]=j; redsm[w][a]=sm; }
  }
  __syncthreads();
  if (t < MT){
    int a=t;
    float V=INFINITY; int J=0; int S=0x7fffffff; bool first=true;
    for (int q=0;q<8;q++){
      float v2=redv[q][a]; int j2=redj[q][a];
      if (first || v2<V || (v2==V && j2<J)){ V=v2; J=j2; first=false; }
      int s2=redsm[q][a]; S=(s2<S)?s2:S;
    }
    bool anyneg = (V < INFINITY);
    finNeg[a] = (S != 0x7fffffff) ? S : J;
    finVal[a] = (anypw[a0+a] != 0 && anyneg) ? 1 : 0;
  }
  __syncthreads();

  // per-anchor triplet loss recomputed from embeddings (+EPS inside norm)
  float lsum=0.0f, lcnt=0.0f;
  for (int a=0;a<MT;a++){
    if (t<256 && finVal[a]){            // dims handled by first 4 waves
      int hp = hpw[a0+a]; int ng = finNeg[a];
      float ai = E[(size_t)(a0+a)*DIM + t];
      float pv = E[(size_t)hp*DIM + t];
      float nv = E[(size_t)ng*DIM + t];
      float dp = ai - pv + EPSF; float dn = ai - nv + EPSF;
      float sp = dp*dp, sn = dn*dn;
      #pragma unroll
      for (int off=32; off; off>>=1){ sp += __shfl_xor(sp,off); sn += __shfl_xor(sn,off); }
      if (l==0){ redp[w]=sp; redn[w]=sn; }
    }
    __syncthreads();
    if (t==0 && finVal[a]){
      float SP=(redp[0]+redp[1])+(redp[2]+redp[3]);
      float SN=(redn[0]+redn[1])+(redn[2]+redn[3]);
      lsum += fmaxf(sqrtf(SP)-sqrtf(SN)+MARGINF, 0.0f);
      lcnt += 1.0f;
    }
    __syncthreads();
  }
  if (t==0){ partials[2*blockIdx.x]=lsum; partials[2*blockIdx.x+1]=lcnt; }
}

// ------ kernel 2 (fallback, no-transpose): round-3 k_main verbatim ------
__global__ __launch_bounds__(256,2) void k_main(const float* __restrict__ E, const int* __restrict__ labels,
     const float* __restrict__ sq, const float* __restrict__ apw, const int* __restrict__ hpw,
     const int* __restrict__ anypw, float* __restrict__ partials){
  __shared__ float4 At[MI*68 + 4];
  __shared__ float redv[4][MI]; __shared__ int redj[4][MI]; __shared__ int redsm[4][MI];
  __shared__ int finNeg[MI]; __shared__ int finVal[MI];
  __shared__ float redp[4], redn[4];
  int t=threadIdx.x, lane=t&63, w=t>>6;
  int a0 = blockIdx.x * MI;
  const float4* E4 = (const float4*)E;
  for (int idx=t; idx<MI*64; idx+=256){
    int a=idx>>6, q=idx&63, pp=q&3, mm=q>>2;
    At[a*68 + pp*17 + mm] = E4[(size_t)(a0+a)*D4 + q];
  }
  __syncthreads();
  float apv[MI], sqi[MI]; int labi[MI];
  #pragma unroll
  for (int a=0;a<MI;a++){ apv[a]=apw[a0+a]; sqi[a]=sq[a0+a]; labi[a]=labels[a0+a]; }
  float mnv[MI]; int mnj[MI]; int smj[MI];
  #pragma unroll
  for (int a=0;a<MI;a++){ mnv[a]=INFINITY; mnj[a]=0; smj[a]=0x7fffffff; }
  int s = t>>2, p = t&3;
  for (int it=0; it<16; it++){
    int colb = it*256 + 4*s;
    const float4* __restrict__ bp = E4 + (size_t)colb*D4 + p;
    float acc[MI][4];
    #pragma unroll
    for (int a=0;a<MI;a++){
      #pragma unroll
      for (int c2=0;c2<4;c2++) acc[a][c2]=0.0f;
    }
    for (int mg=0; mg<4; mg++){
      float4 b[4][4];
      #pragma unroll
      for (int c2=0;c2<4;c2++){
        #pragma unroll
        for (int m=0;m<4;m++) b[m][c2] = bp[(size_t)c2*D4 + mg*16 + m*4];
      }
      #pragma unroll
      for (int a=0;a<MI;a++){
        float4 a4[4];
        #pragma unroll
        for (int m=0;m<4;m++) a4[m] = At[a*68 + p*17 + mg*4 + m];
        #pragma unroll
        for (int m=0;m<4;m++){
          #pragma unroll
          for (int c2=0;c2<4;c2++) acc[a][c2] = fma4(a4[m], b[m][c2], acc[a][c2]);
        }
      }
    }
    #pragma unroll
    for (int a=0;a<MI;a++){
      #pragma unroll
      for (int c2=0;c2<4;c2++){
        float v = acc[a][c2];
        v += __shfl_xor(v,1); v += __shfl_xor(v,2);
        acc[a][c2] = v;
      }
    }
    #pragma unroll
    for (int c2=0;c2<4;c2++){
      int j = colb + c2;
      int lj = labels[j]; float sqj = sq[j];
      #pragma unroll
      for (int a=0;a<MI;a++){
        float d = sqrtf(fmaxf(sqi[a]+sqj-2.0f*acc[a][c2], 0.0f));
        if (lj != labi[a]){
          if (d < mnv[a]){ mnv[a]=d; mnj[a]=j; }
          if (d > apv[a] && d < apv[a]+MARGINF && j < smj[a]) smj[a]=j;
        }
      }
    }
  }
  #pragma unroll
  for (int a=0;a<MI;a++){
    float v=mnv[a]; int j=mnj[a]; int sm=smj[a];
    #pragma unroll
    for (int off=32; off; off>>=1){
      float v2=__shfl_xor(v,off); int j2=__shfl_xor(j,off); int s2=__shfl_xor(sm,off);
      if (v2<v || (v2==v && j2<j)){ v=v2; j=j2; }
      sm = (s2<sm)?s2:sm;
    }
    if (lane==0){ redv[w][a]=v; redj[w][a]=j; redsm[w][a]=sm; }
  }
  __syncthreads();
  if (t < MI){
    int a=t;
    float V=INFINITY; int J=0; int S=0x7fffffff; bool first=true;
    for (int q=0;q<4;q++){
      float v2=redv[q][a]; int j2=redj[q][a];
      if (first || v2<V || (v2==V && j2<J)){ V=v2; J=j2; first=false; }
      int s2=redsm[q][a]; S=(s2<S)?s2:S;
    }
    bool anyneg = (V < INFINITY);
    finNeg[a] = (S != 0x7fffffff) ? S : J;
    finVal[a] = (anypw[a0+a] != 0 && anyneg) ? 1 : 0;
  }
  __syncthreads();
  float lsum=0.0f, lcnt=0.0f;
  for (int a=0;a<MI;a++){
    if (finVal[a]){
      int hp = hpw[a0+a]; int ng = finNeg[a];
      float ai = E[(size_t)(a0+a)*DIM + t];
      float pv = E[(size_t)hp*DIM + t];
      float nv = E[(size_t)ng*DIM + t];
      float dp = ai - pv + EPSF; float dn = ai - nv + EPSF;
      float sp = dp*dp, sn = dn*dn;
      #pragma unroll
      for (int off=32; off; off>>=1){ sp += __shfl_xor(sp,off); sn += __shfl_xor(sn,off); }
      if (lane==0){ redp[w]=sp; redn[w]=sn; }
    }
    __syncthreads();
    if (finVal[a] && t==0){
      float SP=(redp[0]+redp[1])+(redp[2]+redp[3]);
      float SN=(redn[0]+redn[1])+(redn[2]+redn[3]);
      lsum += fmaxf(sqrtf(SP)-sqrtf(SN)+MARGINF, 0.0f);
      lcnt += 1.0f;
    }
    __syncthreads();
  }
  if (t==0){ partials[2*blockIdx.x]=lsum; partials[2*blockIdx.x+1]=lcnt; }
}

// ---------------- kernel 3: final deterministic reduce ----------------
__global__ __launch_bounds__(256) void k_fin(const float* __restrict__ partials, float* __restrict__ out, int nb){
  __shared__ float rs[4], rc[4];
  int t=threadIdx.x, lane=t&63, w=t>>6;
  float s=0.f, c=0.f;
  for (int q=t;q<nb;q+=256){ s+=partials[2*q]; c+=partials[2*q+1]; }
  #pragma unroll
  for (int off=32; off; off>>=1){ s+=__shfl_xor(s,off); c+=__shfl_xor(c,off); }
  if (lane==0){ rs[w]=s; rc[w]=c; }
  __syncthreads();
  if (t==0){
    float S=(rs[0]+rs[1])+(rs[2]+rs[3]);
    float C=(rc[0]+rc[1])+(rc[2]+rc[3]);
    out[0] = (C>0.0f) ? S/fmaxf(C,1.0f) : 0.0f;
  }
}

extern "C" void kernel_launch(void* const* d_in, const int* in_sizes, int n_in,
                              void* d_out, int out_size, void* d_ws, size_t ws_size,
                              hipStream_t stream) {
  const float* E      = (const float*)d_in[0];   // 4096x256 fp32
  const int*   labels = (const int*)d_in[1];     // 4096 int32
  float* out = (float*)d_out;

  float* sqw      = (float*)d_ws;          // 4096 f
  float* apw      = sqw + BN;              // 4096 f
  int*   hpw      = (int*)(apw + BN);      // 4096 i
  int*   anypw    = hpw + BN;              // 4096 i
  float* partials = (float*)(anypw + BN);  // up to 1024 f (ends at 67.6 KB)
  float* ET       = (float*)((char*)d_ws + 131072);  // 4 MB, 128 KB-aligned
  bool big = ws_size >= (size_t)(131072 + 4*1024*1024);

  k_sq  <<<BN/256, 256, 0, stream>>>(E, sqw);
  k_pos <<<256,    256, 0, stream>>>(E, labels, sqw, apw, hpw, anypw);
  if (big){
    k_tr    <<<256,   256, 0, stream>>>(E, ET);
    k_main_t<<<BN/MT, 512, 0, stream>>>(E, ET, labels, sqw, apw, hpw, anypw, partials);
    k_fin   <<<1,     256, 0, stream>>>(partials, out, BN/MT);
  } else {
    k_main  <<<BN/MI, 256, 0, stream>>>(E, labels, sqw, apw, hpw, anypw, partials);
    k_fin   <<<1,     256, 0, stream>>>(partials, out, BN/MI);
  }
}

// Round 6
// 209.062 us; speedup vs baseline: 1.1678x; 1.1678x over previous
//
#include <hip/hip_runtime.h>
#include <math.h>

#define BN 4096
#define DIM 256
#define D4 (DIM/4)        // 64 float4 per row
#define MI 8              // anchors per workgroup (fallback k_main)
#define MT 16             // anchors per workgroup (transpose-path k_main_t)
#define MARGINF 0.3f
#define EPSF 1e-6f
#define SCAP 96           // staged class-member rows in k_pos (fallback)
#define IMAX 0x7fffffff

typedef float v2f __attribute__((ext_vector_type(2)));

// Guaranteed packed FMA: acc{lo,hi} += splat(A.lo or A.hi) * b{lo,hi}
// A operand in VGPR pair; op_sel broadcasts one 32-bit half to both lanes.
#define PKFMA_LO(acc, a2, b2) \
  asm("v_pk_fma_f32 %0, %1, %2, %0 op_sel:[0,0,0] op_sel_hi:[0,1,1]" \
      : "+v"(acc) : "v"(a2), "v"(b2))
#define PKFMA_HI(acc, a2, b2) \
  asm("v_pk_fma_f32 %0, %1, %2, %0 op_sel:[1,0,0] op_sel_hi:[1,1,1]" \
      : "+v"(acc) : "v"(a2), "v"(b2))

__device__ __forceinline__ float fma4(float4 a, float4 b, float c){
  return fmaf(a.x,b.x, fmaf(a.y,b.y, fmaf(a.z,b.z, fmaf(a.w,b.w, c))));
}

// ------- kernel A: transpose E -> ET, per-row sq, zero counter (one kernel) -------
// grid = 64 blocks x 256 threads; block owns 64 rows x all 256 dims.
__global__ __launch_bounds__(256) void k_pre(const float* __restrict__ E, float* __restrict__ ET,
                                             float* __restrict__ sq, unsigned int* __restrict__ counter){
  __shared__ float tile[64][257];
  int t = threadIdx.x;
  int r0 = blockIdx.x * 64;
  const float4* E4 = (const float4*)E;
  for (int idx=t; idx<64*64; idx+=256){
    int row = idx>>6, c4 = idx&63;
    float4 v = E4[(size_t)(r0+row)*D4 + c4];
    tile[row][c4*4+0]=v.x; tile[row][c4*4+1]=v.y; tile[row][c4*4+2]=v.z; tile[row][c4*4+3]=v.w;
  }
  __syncthreads();
  if (t < 64){
    float s0=0.f,s1=0.f;
    #pragma unroll
    for (int k=0;k<DIM;k+=2){
      float x0=tile[t][k], x1=tile[t][k+1];
      s0=fmaf(x0,x0,s0); s1=fmaf(x1,x1,s1);
    }
    sq[r0+t] = s0+s1;
  }
  float4* ET4 = (float4*)ET;
  for (int idx=t; idx<256*16; idx+=256){
    int k = idx>>4, c = idx&15;
    float4 v;
    v.x = tile[c*4+0][k]; v.y = tile[c*4+1][k];
    v.z = tile[c*4+2][k]; v.w = tile[c*4+3][k];
    ET4[(size_t)k*1024 + (r0>>2) + c] = v;
  }
  if (blockIdx.x==0 && t==0) counter[0] = 0u;
}

// ------- kernel B: GEMM + full mining (pos+neg+semi) + loss + final reduce -------
// grid = 256 blocks x 512 threads, 16 anchors each. Merged k-loop covers both
// column groups (8 cols/lane total); all 128 dots live in registers; hardest-
// positive computed block-locally (block sees all 4096 candidates); last block
// to finish does the deterministic final reduce.
__global__ __launch_bounds__(512,2) void k_main_t(const float* __restrict__ E, const float* __restrict__ ET,
     const int* __restrict__ labels, const float* __restrict__ sq,
     float* __restrict__ partials, unsigned int* __restrict__ counter, float* __restrict__ out){
  __shared__ float rpv[8][MT]; __shared__ int rpj[8][MT];
  __shared__ float rnv[8][MT]; __shared__ int rnj[8][MT]; __shared__ int rsm[8][MT];
  __shared__ float apS[MT]; __shared__ int hpS[MT]; __shared__ int posOk[MT];
  __shared__ int finNeg[MT]; __shared__ int finVal[MT];
  __shared__ float lossS[MT];
  __shared__ float rs[8], rc[8];
  __shared__ int lastFlag;
  int t=threadIdx.x, l=t&63, w=t>>6;
  int a0 = blockIdx.x * MT;
  const float4* E4  = (const float4*)E;
  const float4* ET4 = (const float4*)ET;

  // ---------------- merged K-loop: 16 anchors x 8 cols/lane ----------------
  v2f acc[MT][4];           // [a][grp*2+half] : 128 VGPR
  #pragma unroll
  for (int a=0;a<MT;a++){ acc[a][0]=(v2f)(0.f); acc[a][1]=(v2f)(0.f); acc[a][2]=(v2f)(0.f); acc[a][3]=(v2f)(0.f); }
  const float4* p0 = ET4 + w*64 + l;          // group 0: cols w*256+4l..+3
  const float4* p1 = p0 + 8*64;               // group 1: +2048 cols
  for (int kb=0; kb<64; kb++){
    float4 e0=p0[0], e1=p0[1024], e2=p0[2048], e3=p0[3072];
    float4 f0=p1[0], f1=p1[1024], f2=p1[2048], f3=p1[3072];
    p0 += 4096; p1 += 4096;
    v2f e0l={e0.x,e0.y}, e0h={e0.z,e0.w};
    v2f e1l={e1.x,e1.y}, e1h={e1.z,e1.w};
    v2f e2l={e2.x,e2.y}, e2h={e2.z,e2.w};
    v2f e3l={e3.x,e3.y}, e3h={e3.z,e3.w};
    v2f f0l={f0.x,f0.y}, f0h={f0.z,f0.w};
    v2f f1l={f1.x,f1.y}, f1h={f1.z,f1.w};
    v2f f2l={f2.x,f2.y}, f2h={f2.z,f2.w};
    v2f f3l={f3.x,f3.y}, f3h={f3.z,f3.w};
    #pragma unroll
    for (int a=0;a<MT;a++){
      float4 av = E4[(a0+a)*D4 + kb];         // wave-uniform broadcast load
      v2f a01 = {av.x, av.y}, a23 = {av.z, av.w};
      PKFMA_LO(acc[a][0], a01, e0l); PKFMA_LO(acc[a][1], a01, e0h);
      PKFMA_HI(acc[a][0], a01, e1l); PKFMA_HI(acc[a][1], a01, e1h);
      PKFMA_LO(acc[a][0], a23, e2l); PKFMA_LO(acc[a][1], a23, e2h);
      PKFMA_HI(acc[a][0], a23, e3l); PKFMA_HI(acc[a][1], a23, e3h);
      PKFMA_LO(acc[a][2], a01, f0l); PKFMA_LO(acc[a][3], a01, f0h);
      PKFMA_HI(acc[a][2], a01, f1l); PKFMA_HI(acc[a][3], a01, f1h);
      PKFMA_LO(acc[a][2], a23, f2l); PKFMA_LO(acc[a][3], a23, f2h);
      PKFMA_HI(acc[a][2], a23, f3l); PKFMA_HI(acc[a][3], a23, f3h);
    }
  }

  // ---------------- distances (in registers) ----------------
  int colb0 = w*256 + 4*l, colb1 = colb0 + 2048;
  int4   lj0 = *(const int4*  )(labels + colb0);
  int4   lj1 = *(const int4*  )(labels + colb1);
  float4 sj0 = *(const float4*)(sq + colb0);
  float4 sj1 = *(const float4*)(sq + colb1);
  int   ljv[8] = {lj0.x,lj0.y,lj0.z,lj0.w, lj1.x,lj1.y,lj1.z,lj1.w};
  float sjv[8] = {sj0.x,sj0.y,sj0.z,sj0.w, sj1.x,sj1.y,sj1.z,sj1.w};
  int   jv[8];
  #pragma unroll
  for (int c=0;c<4;c++){ jv[c]=colb0+c; jv[4+c]=colb1+c; }
  float d_[MT][8];
  #pragma unroll
  for (int a=0;a<MT;a++){
    float sqa = sq[a0+a];
    float dot[8] = {acc[a][0].x, acc[a][0].y, acc[a][1].x, acc[a][1].y,
                    acc[a][2].x, acc[a][2].y, acc[a][3].x, acc[a][3].y};
    #pragma unroll
    for (int c=0;c<8;c++) d_[a][c] = sqrtf(fmaxf(sqa + sjv[c] - 2.0f*dot[c], 0.0f));
  }

  // ---------------- pass 2a: hardest positive per anchor ----------------
  #pragma unroll
  for (int a=0;a<MT;a++){
    int labi = labels[a0+a]; int self = a0+a;
    float bv=-INFINITY; int bj=IMAX;
    #pragma unroll
    for (int c=0;c<8;c++){                    // jv ascending within thread
      int j = jv[c];
      if (ljv[c]==labi && j!=self){
        float d = d_[a][c];
        if (d > bv || (d==bv && j<bj)){ bv=d; bj=j; }
      }
    }
    #pragma unroll
    for (int off=32; off; off>>=1){
      float v2=__shfl_xor(bv,off); int j2=__shfl_xor(bj,off);
      if (v2>bv || (v2==bv && j2<bj)){ bv=v2; bj=j2; }
    }
    if (l==0){ rpv[w][a]=bv; rpj[w][a]=bj; }
  }
  __syncthreads();
  if (t < MT){
    int a=t;
    float V=-INFINITY; int J=IMAX;
    for (int q=0;q<8;q++){
      float v2=rpv[q][a]; int j2=rpj[q][a];
      if (v2>V || (v2==V && j2<J)){ V=v2; J=j2; }
    }
    posOk[a] = (J != IMAX);
    apS[a] = V;                               // -inf if no positive (anchor invalid)
    hpS[a] = (J==IMAX) ? 0 : J;
  }
  __syncthreads();

  // ---------------- pass 2b: hardest-neg + first semi-hard ----------------
  #pragma unroll
  for (int a=0;a<MT;a++){
    int labi = labels[a0+a];
    float ap = apS[a]; float aphi = ap + MARGINF;
    float mn=INFINITY; int mj=IMAX; int sm=IMAX;
    #pragma unroll
    for (int c=0;c<8;c++){
      int j = jv[c];
      if (ljv[c] != labi){
        float d = d_[a][c];
        if (d < mn){ mn=d; mj=j; }            // strict <: first min (ascending j)
        if (d > ap && d < aphi && j < sm) sm=j;
      }
    }
    #pragma unroll
    for (int off=32; off; off>>=1){
      float v2=__shfl_xor(mn,off); int j2=__shfl_xor(mj,off); int s2=__shfl_xor(sm,off);
      if (v2<mn || (v2==mn && j2<mj)){ mn=v2; mj=j2; }
      sm = (s2<sm)?s2:sm;
    }
    if (l==0){ rnv[w][a]=mn; rnj[w][a]=mj; rsm[w][a]=sm; }
  }
  __syncthreads();
  if (t < MT){
    int a=t;
    float V=INFINITY; int J=IMAX; int S=IMAX;
    for (int q=0;q<8;q++){
      float v2=rnv[q][a]; int j2=rnj[q][a];
      if (v2<V || (v2==V && j2<J)){ V=v2; J=j2; }
      int s2=rsm[q][a]; S=(s2<S)?s2:S;
    }
    bool anyneg = (J != IMAX);
    int ng = (S != IMAX) ? S : J;
    finNeg[a] = (ng==IMAX) ? 0 : ng;
    finVal[a] = (posOk[a] && anyneg) ? 1 : 0;
  }
  __syncthreads();

  // ------- loss epilogue: half-wave (32 lanes) per anchor, 1 barrier -------
  {
    int a = 2*w + (l>>5);                     // wave w: anchors 2w, 2w+1
    int l32 = l & 31;
    float sp=0.f, sn=0.f;
    int dov = finVal[a];
    if (dov){
      int hp = hpS[a], ng = finNeg[a];
      const float4* ar = (const float4*)(E + (size_t)(a0+a)*DIM) + l32*2;
      const float4* pr = (const float4*)(E + (size_t)hp*DIM)     + l32*2;
      const float4* nr = (const float4*)(E + (size_t)ng*DIM)     + l32*2;
      #pragma unroll
      for (int h=0; h<2; h++){
        float4 av = ar[h], pv = pr[h], nv = nr[h];
        float d0=av.x-pv.x+EPSF, d1=av.y-pv.y+EPSF, d2=av.z-pv.z+EPSF, d3=av.w-pv.w+EPSF;
        sp = fmaf(d0,d0, fmaf(d1,d1, fmaf(d2,d2, fmaf(d3,d3, sp))));
        float n0=av.x-nv.x+EPSF, n1=av.y-nv.y+EPSF, n2=av.z-nv.z+EPSF, n3=av.w-nv.w+EPSF;
        sn = fmaf(n0,n0, fmaf(n1,n1, fmaf(n2,n2, fmaf(n3,n3, sn))));
      }
    }
    #pragma unroll
    for (int off=16; off; off>>=1){ sp += __shfl_xor(sp,off); sn += __shfl_xor(sn,off); }
    if (l32==0) lossS[a] = dov ? fmaxf(sqrtf(sp)-sqrtf(sn)+MARGINF, 0.0f) : 0.0f;
  }
  __syncthreads();

  // ------- per-block partial + last-block final reduce -------
  if (t==0){
    float lsum=0.f, lcnt=0.f;
    for (int a=0;a<MT;a++){ lsum += lossS[a]; lcnt += (float)finVal[a]; }
    partials[2*blockIdx.x]   = lsum;
    partials[2*blockIdx.x+1] = lcnt;
    __threadfence();
    unsigned int old = atomicAdd(counter, 1u);
    lastFlag = (old == gridDim.x - 1) ? 1 : 0;
  }
  __syncthreads();
  if (lastFlag){
    __threadfence();
    float s=0.f, c=0.f;
    for (int q=t; q<256; q+=512){ s += partials[2*q]; c += partials[2*q+1]; }
    #pragma unroll
    for (int off=32; off; off>>=1){ s += __shfl_xor(s,off); c += __shfl_xor(c,off); }
    if (l==0){ rs[w]=s; rc[w]=c; }
    __syncthreads();
    if (t==0){
      float S=0.f, C=0.f;
      for (int q=0;q<8;q++){ S+=rs[q]; C+=rc[q]; }
      out[0] = (C>0.0f) ? S/fmaxf(C,1.0f) : 0.0f;
    }
  }
}

// ================= fallback path (small workspace) =================
__global__ __launch_bounds__(256) void k_sq(const float* __restrict__ E, float* __restrict__ sq){
  int i = blockIdx.x*256 + threadIdx.x;
  if (i >= BN) return;
  const float4* r = (const float4*)E + (size_t)i*D4;
  float a0=0.f,a1=0.f,a2=0.f,a3=0.f;
  #pragma unroll
  for (int q=0;q<D4;q+=4){
    a0 = fma4(r[q],r[q],a0);   a1 = fma4(r[q+1],r[q+1],a1);
    a2 = fma4(r[q+2],r[q+2],a2); a3 = fma4(r[q+3],r[q+3],a3);
  }
  sq[i] = (a0+a1)+(a2+a3);
}

__global__ __launch_bounds__(256) void k_pos(const float* __restrict__ E, const int* __restrict__ labels,
                       const float* __restrict__ sq, float* __restrict__ apw,
                       int* __restrict__ hpw, int* __restrict__ anypw){
  __shared__ int members[1024];
  __shared__ float4 mem4[SCAP*65];
  __shared__ int cnts[16][4];
  __shared__ int offs[16][4];
  __shared__ int cntS;
  int t = threadIdx.x, lane = t&63, w = t>>6;
  int c = blockIdx.x >> 2, split = blockIdx.x & 3;
  for (int ch=0; ch<16; ch++){
    bool m = (labels[ch*256 + t] == c);
    unsigned long long mask = __ballot(m);
    if (lane==0) cnts[ch][w] = __popcll(mask);
  }
  __syncthreads();
  if (t==0){
    int run=0;
    for (int ch=0; ch<16; ch++)
      for (int q=0;q<4;q++){ offs[ch][q]=run; run+=cnts[ch][q]; }
    cntS = run;
  }
  __syncthreads();
  int cnt = cntS; if (cnt>1024) cnt=1024;
  for (int ch=0; ch<16; ch++){
    int idx = ch*256 + t;
    bool m = (labels[idx] == c);
    unsigned long long mask = __ballot(m);
    int my = __popcll(mask & ((1ull<<lane)-1ull));
    int pos = offs[ch][w] + my;
    if (m && pos < 1024) members[pos] = idx;
  }
  int S = (cnt < SCAP) ? cnt : SCAP;
  int anyp = (cnt >= 2) ? 1 : 0;
  __syncthreads();
  const float4* E4 = (const float4*)E;
  for (int idx=t; idx<S*64; idx+=256){
    int row = idx>>6, f = idx&63;
    mem4[row*65 + f] = E4[(size_t)members[row]*D4 + f];
  }
  __syncthreads();
  int esplit = split*4 + w;
  int p = lane&3, cand = lane>>2;
  int passes = (cnt+15)>>4;
  for (int mi=esplit; mi<cnt; mi+=16){
    int i = members[mi];
    float sqi = sq[i];
    float4 ai4[16];
    if (mi < S){
      #pragma unroll
      for (int m=0;m<16;m++) ai4[m] = mem4[mi*65 + p + 4*m];
    } else {
      #pragma unroll
      for (int m=0;m<16;m++) ai4[m] = E4[(size_t)i*D4 + p + 4*m];
    }
    float bv = -INFINITY; int bj = IMAX;
    for (int ps=0; ps<passes; ps++){
      int mj = ps*16 + cand;
      if (mj < cnt && mj != mi){
        int j = members[mj];
        float a0v=0.f, a1v=0.f;
        if (mj < S){
          const float4* rj = mem4 + mj*65 + p;
          #pragma unroll
          for (int m=0;m<16;m+=2){ a0v=fma4(ai4[m],rj[4*m],a0v); a1v=fma4(ai4[m+1],rj[4*(m+1)],a1v); }
        } else {
          const float4* rj = E4 + (size_t)j*D4 + p;
          #pragma unroll
          for (int m=0;m<16;m+=2){ a0v=fma4(ai4[m],rj[4*m],a0v); a1v=fma4(ai4[m+1],rj[4*(m+1)],a1v); }
        }
        float acc = a0v+a1v;
        acc += __shfl_xor(acc,1); acc += __shfl_xor(acc,2);
        float d = sqrtf(fmaxf(sqi + sq[j] - 2.0f*acc, 0.0f));
        if (p==0){ if (d > bv || (d==bv && j<bj)){ bv=d; bj=j; } }
      }
    }
    #pragma unroll
    for (int off=32; off; off>>=1){
      float v2=__shfl_xor(bv,off); int j2=__shfl_xor(bj,off);
      if (v2>bv || (v2==bv && j2<bj)){ bv=v2; bj=j2; }
    }
    if (lane==0){
      int J = (bj==IMAX) ? 0 : bj;
      apw[i]=bv; hpw[i]=J; anypw[i]=anyp;
    }
  }
}

__global__ __launch_bounds__(256,2) void k_main(const float* __restrict__ E, const int* __restrict__ labels,
     const float* __restrict__ sq, const float* __restrict__ apw, const int* __restrict__ hpw,
     const int* __restrict__ anypw, float* __restrict__ partials){
  __shared__ float4 At[MI*68 + 4];
  __shared__ float redv[4][MI]; __shared__ int redj[4][MI]; __shared__ int redsm[4][MI];
  __shared__ int finNeg[MI]; __shared__ int finVal[MI];
  __shared__ float redp[4], redn[4];
  int t=threadIdx.x, lane=t&63, w=t>>6;
  int a0 = blockIdx.x * MI;
  const float4* E4 = (const float4*)E;
  for (int idx=t; idx<MI*64; idx+=256){
    int a=idx>>6, q=idx&63, pp=q&3, mm=q>>2;
    At[a*68 + pp*17 + mm] = E4[(size_t)(a0+a)*D4 + q];
  }
  __syncthreads();
  float apv[MI], sqi[MI]; int labi[MI];
  #pragma unroll
  for (int a=0;a<MI;a++){ apv[a]=apw[a0+a]; sqi[a]=sq[a0+a]; labi[a]=labels[a0+a]; }
  float mnv[MI]; int mnj[MI]; int smj[MI];
  #pragma unroll
  for (int a=0;a<MI;a++){ mnv[a]=INFINITY; mnj[a]=0; smj[a]=IMAX; }
  int s = t>>2, p = t&3;
  for (int it=0; it<16; it++){
    int colb = it*256 + 4*s;
    const float4* __restrict__ bp = E4 + (size_t)colb*D4 + p;
    float acc[MI][4];
    #pragma unroll
    for (int a=0;a<MI;a++){
      #pragma unroll
      for (int c2=0;c2<4;c2++) acc[a][c2]=0.0f;
    }
    for (int mg=0; mg<4; mg++){
      float4 b[4][4];
      #pragma unroll
      for (int c2=0;c2<4;c2++){
        #pragma unroll
        for (int m=0;m<4;m++) b[m][c2] = bp[(size_t)c2*D4 + mg*16 + m*4];
      }
      #pragma unroll
      for (int a=0;a<MI;a++){
        float4 a4[4];
        #pragma unroll
        for (int m=0;m<4;m++) a4[m] = At[a*68 + p*17 + mg*4 + m];
        #pragma unroll
        for (int m=0;m<4;m++){
          #pragma unroll
          for (int c2=0;c2<4;c2++) acc[a][c2] = fma4(a4[m], b[m][c2], acc[a][c2]);
        }
      }
    }
    #pragma unroll
    for (int a=0;a<MI;a++){
      #pragma unroll
      for (int c2=0;c2<4;c2++){
        float v = acc[a][c2];
        v += __shfl_xor(v,1); v += __shfl_xor(v,2);
        acc[a][c2] = v;
      }
    }
    #pragma unroll
    for (int c2=0;c2<4;c2++){
      int j = colb + c2;
      int lj = labels[j]; float sqj = sq[j];
      #pragma unroll
      for (int a=0;a<MI;a++){
        float d = sqrtf(fmaxf(sqi[a]+sqj-2.0f*acc[a][c2], 0.0f));
        if (lj != labi[a]){
          if (d < mnv[a]){ mnv[a]=d; mnj[a]=j; }
          if (d > apv[a] && d < apv[a]+MARGINF && j < smj[a]) smj[a]=j;
        }
      }
    }
  }
  #pragma unroll
  for (int a=0;a<MI;a++){
    float v=mnv[a]; int j=mnj[a]; int sm=smj[a];
    #pragma unroll
    for (int off=32; off; off>>=1){
      float v2=__shfl_xor(v,off); int j2=__shfl_xor(j,off); int s2=__shfl_xor(sm,off);
      if (v2<v || (v2==v && j2<j)){ v=v2; j=j2; }
      sm = (s2<sm)?s2:sm;
    }
    if (lane==0){ redv[w][a]=v; redj[w][a]=j; redsm[w][a]=sm; }
  }
  __syncthreads();
  if (t < MI){
    int a=t;
    float V=INFINITY; int J=0; int S=IMAX; bool first=true;
    for (int q=0;q<4;q++){
      float v2=redv[q][a]; int j2=redj[q][a];
      if (first || v2<V || (v2==V && j2<J)){ V=v2; J=j2; first=false; }
      int s2=redsm[q][a]; S=(s2<S)?s2:S;
    }
    bool anyneg = (V < INFINITY);
    finNeg[a] = (S != IMAX) ? S : J;
    finVal[a] = (anypw[a0+a] != 0 && anyneg) ? 1 : 0;
  }
  __syncthreads();
  float lsum=0.0f, lcnt=0.0f;
  for (int a=0;a<MI;a++){
    if (finVal[a]){
      int hp = hpw[a0+a]; int ng = finNeg[a];
      float ai = E[(size_t)(a0+a)*DIM + t];
      float pv = E[(size_t)hp*DIM + t];
      float nv = E[(size_t)ng*DIM + t];
      float dp = ai - pv + EPSF; float dn = ai - nv + EPSF;
      float sp = dp*dp, sn = dn*dn;
      #pragma unroll
      for (int off=32; off; off>>=1){ sp += __shfl_xor(sp,off); sn += __shfl_xor(sn,off); }
      if (lane==0){ redp[w]=sp; redn[w]=sn; }
    }
    __syncthreads();
    if (finVal[a] && t==0){
      float SP=(redp[0]+redp[1])+(redp[2]+redp[3]);
      float SN=(redn[0]+redn[1])+(redn[2]+redn[3]);
      lsum += fmaxf(sqrtf(SP)-sqrtf(SN)+MARGINF, 0.0f);
      lcnt += 1.0f;
    }
    __syncthreads();
  }
  if (t==0){ partials[2*blockIdx.x]=lsum; partials[2*blockIdx.x+1]=lcnt; }
}

__global__ __launch_bounds__(256) void k_fin(const float* __restrict__ partials, float* __restrict__ out, int nb){
  __shared__ float rs[4], rc[4];
  int t=threadIdx.x, lane=t&63, w=t>>6;
  float s=0.f, c=0.f;
  for (int q=t;q<nb;q+=256){ s+=partials[2*q]; c+=partials[2*q+1]; }
  #pragma unroll
  for (int off=32; off; off>>=1){ s+=__shfl_xor(s,off); c+=__shfl_xor(c,off); }
  if (lane==0){ rs[w]=s; rc[w]=c; }
  __syncthreads();
  if (t==0){
    float S=(rs[0]+rs[1])+(rs[2]+rs[3]);
    float C=(rc[0]+rc[1])+(rc[2]+rc[3]);
    out[0] = (C>0.0f) ? S/fmaxf(C,1.0f) : 0.0f;
  }
}

extern "C" void kernel_launch(void* const* d_in, const int* in_sizes, int n_in,
                              void* d_out, int out_size, void* d_ws, size_t ws_size,
                              hipStream_t stream) {
  const float* E      = (const float*)d_in[0];   // 4096x256 fp32
  const int*   labels = (const int*)d_in[1];     // 4096 int32
  float* out = (float*)d_out;

  float* sqw      = (float*)d_ws;          // 4096 f
  float* apw      = sqw + BN;              // 4096 f   (fallback only)
  int*   hpw      = (int*)(apw + BN);      // 4096 i   (fallback only)
  int*   anypw    = hpw + BN;              // 4096 i   (fallback only)
  float* partials = (float*)(anypw + BN);  // 1024 f
  unsigned int* counter = (unsigned int*)(partials + 1024);
  float* ET       = (float*)((char*)d_ws + 131072);  // 4 MB, 128 KB-aligned
  bool big = ws_size >= (size_t)(131072 + 4*1024*1024);

  if (big){
    k_pre   <<<64,    256, 0, stream>>>(E, ET, sqw, counter);
    k_main_t<<<BN/MT, 512, 0, stream>>>(E, ET, labels, sqw, partials, counter, out);
  } else {
    k_sq  <<<BN/256, 256, 0, stream>>>(E, sqw);
    k_pos <<<256,    256, 0, stream>>>(E, labels, sqw, apw, hpw, anypw);
    k_main<<<BN/MI,  256, 0, stream>>>(E, labels, sqw, apw, hpw, anypw, partials);
    k_fin <<<1,      256, 0, stream>>>(partials, out, BN/MI);
  }
}

// Round 7
// 199.290 us; speedup vs baseline: 1.2251x; 1.0490x over previous
//
#include <hip/hip_runtime.h>
#include <math.h>

#define BN 4096
#define DIM 256
#define D4 (DIM/4)        // 64 float4 per row
#define MI 8              // anchors per workgroup (fallback k_main)
#define MT 16             // anchors per workgroup (transpose-path k_main_t)
#define MARGINF 0.3f
#define EPSF 1e-6f
#define SCAP 96           // staged class-member rows in k_pos (fallback)
#define IMAX 0x7fffffff

typedef float v2f __attribute__((ext_vector_type(2)));

// Guaranteed packed FMA: acc{lo,hi} += splat(A.lo or A.hi) * b{lo,hi}
// A operand is an SGPR pair (VOP3P permits one scalar source); op_sel
// broadcasts one 32-bit half to both lanes. Zero splat instructions.
#define PKFMA_LO(acc, a2, b2) \
  asm("v_pk_fma_f32 %0, %1, %2, %0 op_sel:[0,0,0] op_sel_hi:[0,1,1]" \
      : "+v"(acc) : "s"(a2), "v"(b2))
#define PKFMA_HI(acc, a2, b2) \
  asm("v_pk_fma_f32 %0, %1, %2, %0 op_sel:[1,0,0] op_sel_hi:[1,1,1]" \
      : "+v"(acc) : "s"(a2), "v"(b2))

__device__ __forceinline__ float fma4(float4 a, float4 b, float c){
  return fmaf(a.x,b.x, fmaf(a.y,b.y, fmaf(a.z,b.z, fmaf(a.w,b.w, c))));
}

// ------- kernel A: transpose E -> ET, per-row sq, zero counter (one kernel) -------
__global__ __launch_bounds__(256) void k_pre(const float* __restrict__ E, float* __restrict__ ET,
                                             float* __restrict__ sq, unsigned int* __restrict__ counter){
  __shared__ float tile[64][257];
  int t = threadIdx.x;
  int r0 = blockIdx.x * 64;
  const float4* E4 = (const float4*)E;
  for (int idx=t; idx<64*64; idx+=256){
    int row = idx>>6, c4 = idx&63;
    float4 v = E4[(size_t)(r0+row)*D4 + c4];
    tile[row][c4*4+0]=v.x; tile[row][c4*4+1]=v.y; tile[row][c4*4+2]=v.z; tile[row][c4*4+3]=v.w;
  }
  __syncthreads();
  if (t < 64){
    float s0=0.f,s1=0.f;
    #pragma unroll
    for (int k=0;k<DIM;k+=2){
      float x0=tile[t][k], x1=tile[t][k+1];
      s0=fmaf(x0,x0,s0); s1=fmaf(x1,x1,s1);
    }
    sq[r0+t] = s0+s1;
  }
  float4* ET4 = (float4*)ET;
  for (int idx=t; idx<256*16; idx+=256){
    int k = idx>>4, c = idx&15;
    float4 v;
    v.x = tile[c*4+0][k]; v.y = tile[c*4+1][k];
    v.z = tile[c*4+2][k]; v.w = tile[c*4+3][k];
    ET4[(size_t)k*1024 + (r0>>2) + c] = v;
  }
  if (blockIdx.x==0 && t==0) counter[0] = 0u;
}

// ------- kernel B: GEMM + full mining + loss + final reduce -------
// v7: 1024-thread blocks (16 waves -> 4 waves/SIMD at 1 block/CU), grid 256.
// Lane owns 4 consecutive cols (wave w covers cols w*256..w*256+255); per-block
// ET read is still exactly one full pass (1 GB L2 total). All dots in VGPRs;
// hardest-positive block-local; last block does the deterministic final reduce.
__global__ __launch_bounds__(1024,4) void k_main_t(const float* __restrict__ E, const float* __restrict__ ET,
     const int* __restrict__ labels, const float* __restrict__ sq,
     float* __restrict__ partials, unsigned int* __restrict__ counter, float* __restrict__ out){
  __shared__ float rpv[16][MT]; __shared__ int rpj[16][MT];
  __shared__ float rnv[16][MT]; __shared__ int rnj[16][MT]; __shared__ int rsm[16][MT];
  __shared__ float apS[MT]; __shared__ int hpS[MT]; __shared__ int posOk[MT];
  __shared__ int finNeg[MT]; __shared__ int finVal[MT];
  __shared__ float lossS[MT];
  __shared__ float rs[16], rc[16];
  __shared__ int lastFlag;
  int t=threadIdx.x, l=t&63, w=t>>6;          // w in 0..15
  int a0 = blockIdx.x * MT;
  const float4* E4  = (const float4*)E;
  const float4* ET4 = (const float4*)ET;

  // ---------------- K-loop: 16 anchors x 4 cols/lane ----------------
  v2f acc[MT][2];                             // 64 VGPR
  #pragma unroll
  for (int a=0;a<MT;a++){ acc[a][0]=(v2f)(0.f); acc[a][1]=(v2f)(0.f); }
  const float4* bp = ET4 + w*64 + l;          // cols w*256+4l..+3; + dim*1024
  for (int kb=0; kb<64; kb++){
    float4 e0=bp[0], e1=bp[1024], e2=bp[2048], e3=bp[3072];
    bp += 4096;
    v2f e0l={e0.x,e0.y}, e0h={e0.z,e0.w};
    v2f e1l={e1.x,e1.y}, e1h={e1.z,e1.w};
    v2f e2l={e2.x,e2.y}, e2h={e2.z,e2.w};
    v2f e3l={e3.x,e3.y}, e3h={e3.z,e3.w};
    #pragma unroll
    for (int a=0;a<MT;a++){
      float4 av = E4[(a0+a)*D4 + kb];         // uniform -> s_load_dwordx4
      v2f a01 = {av.x, av.y}, a23 = {av.z, av.w};
      PKFMA_LO(acc[a][0], a01, e0l); PKFMA_LO(acc[a][1], a01, e0h);
      PKFMA_HI(acc[a][0], a01, e1l); PKFMA_HI(acc[a][1], a01, e1h);
      PKFMA_LO(acc[a][0], a23, e2l); PKFMA_LO(acc[a][1], a23, e2h);
      PKFMA_HI(acc[a][0], a23, e3l); PKFMA_HI(acc[a][1], a23, e3h);
    }
  }

  // ---------------- distances (in registers) ----------------
  int colb = w*256 + 4*l;
  int4   lj4 = *(const int4*  )(labels + colb);
  float4 sj4 = *(const float4*)(sq + colb);
  int   ljv[4] = {lj4.x,lj4.y,lj4.z,lj4.w};
  float sjv[4] = {sj4.x,sj4.y,sj4.z,sj4.w};
  float dm[MT][4];
  #pragma unroll
  for (int a=0;a<MT;a++){
    float sqa = sq[a0+a];
    float dot[4] = {acc[a][0].x, acc[a][0].y, acc[a][1].x, acc[a][1].y};
    #pragma unroll
    for (int c=0;c<4;c++) dm[a][c] = sqrtf(fmaxf(sqa + sjv[c] - 2.0f*dot[c], 0.0f));
  }

  // ---------------- pass 2a: hardest positive per anchor ----------------
  #pragma unroll
  for (int a=0;a<MT;a++){
    int labi = labels[a0+a]; int self = a0+a;
    float bv=-INFINITY; int bj=IMAX;
    #pragma unroll
    for (int c=0;c<4;c++){                    // j ascending within thread
      int j = colb + c;
      if (ljv[c]==labi && j!=self){
        float d = dm[a][c];
        if (d > bv || (d==bv && j<bj)){ bv=d; bj=j; }
      }
    }
    #pragma unroll
    for (int off=32; off; off>>=1){
      float v2=__shfl_xor(bv,off); int j2=__shfl_xor(bj,off);
      if (v2>bv || (v2==bv && j2<bj)){ bv=v2; bj=j2; }
    }
    if (l==0){ rpv[w][a]=bv; rpj[w][a]=bj; }
  }
  __syncthreads();
  if (t < MT){
    int a=t;
    float V=-INFINITY; int J=IMAX;
    for (int q=0;q<16;q++){                   // waves ascending = cols ascending
      float v2=rpv[q][a]; int j2=rpj[q][a];
      if (v2>V || (v2==V && j2<J)){ V=v2; J=j2; }
    }
    posOk[a] = (J != IMAX);
    apS[a] = V;                               // -inf if no positive (anchor invalid)
    hpS[a] = (J==IMAX) ? 0 : J;
  }
  __syncthreads();

  // ---------------- pass 2b: hardest-neg + first semi-hard ----------------
  #pragma unroll
  for (int a=0;a<MT;a++){
    int labi = labels[a0+a];
    float ap = apS[a]; float aphi = ap + MARGINF;
    float mn=INFINITY; int mj=IMAX; int sm=IMAX;
    #pragma unroll
    for (int c=0;c<4;c++){
      int j = colb + c;
      if (ljv[c] != labi){
        float d = dm[a][c];
        if (d < mn){ mn=d; mj=j; }            // strict <: first min (ascending j)
        if (d > ap && d < aphi && j < sm) sm=j;
      }
    }
    #pragma unroll
    for (int off=32; off; off>>=1){
      float v2=__shfl_xor(mn,off); int j2=__shfl_xor(mj,off); int s2=__shfl_xor(sm,off);
      if (v2<mn || (v2==mn && j2<mj)){ mn=v2; mj=j2; }
      sm = (s2<sm)?s2:sm;
    }
    if (l==0){ rnv[w][a]=mn; rnj[w][a]=mj; rsm[w][a]=sm; }
  }
  __syncthreads();
  if (t < MT){
    int a=t;
    float V=INFINITY; int J=IMAX; int S=IMAX;
    for (int q=0;q<16;q++){
      float v2=rnv[q][a]; int j2=rnj[q][a];
      if (v2<V || (v2==V && j2<J)){ V=v2; J=j2; }
      int s2=rsm[q][a]; S=(s2<S)?s2:S;
    }
    bool anyneg = (J != IMAX);
    int ng = (S != IMAX) ? S : J;
    finNeg[a] = (ng==IMAX) ? 0 : ng;
    finVal[a] = (posOk[a] && anyneg) ? 1 : 0;
  }
  __syncthreads();

  // ------- loss epilogue: wave w owns anchor w (4 dims/lane, 1 barrier) -------
  {
    int a = w;
    float sp=0.f, sn=0.f;
    int dov = finVal[a];
    if (dov){
      int hp = hpS[a], ng = finNeg[a];
      float4 av = ((const float4*)(E + (size_t)(a0+a)*DIM))[l];
      float4 pv = ((const float4*)(E + (size_t)hp*DIM))[l];
      float4 nv = ((const float4*)(E + (size_t)ng*DIM))[l];
      float d0=av.x-pv.x+EPSF, d1=av.y-pv.y+EPSF, d2=av.z-pv.z+EPSF, d3=av.w-pv.w+EPSF;
      sp = fmaf(d0,d0, fmaf(d1,d1, fmaf(d2,d2, d3*d3)));
      float n0=av.x-nv.x+EPSF, n1=av.y-nv.y+EPSF, n2=av.z-nv.z+EPSF, n3=av.w-nv.w+EPSF;
      sn = fmaf(n0,n0, fmaf(n1,n1, fmaf(n2,n2, n3*n3)));
    }
    #pragma unroll
    for (int off=32; off; off>>=1){ sp += __shfl_xor(sp,off); sn += __shfl_xor(sn,off); }
    if (l==0) lossS[a] = dov ? fmaxf(sqrtf(sp)-sqrtf(sn)+MARGINF, 0.0f) : 0.0f;
  }
  __syncthreads();

  // ------- per-block partial + last-block final reduce -------
  if (t==0){
    float lsum=0.f, lcnt=0.f;
    for (int a=0;a<MT;a++){ lsum += lossS[a]; lcnt += (float)finVal[a]; }
    partials[2*blockIdx.x]   = lsum;
    partials[2*blockIdx.x+1] = lcnt;
    __threadfence();
    unsigned int old = atomicAdd(counter, 1u);
    lastFlag = (old == gridDim.x - 1) ? 1 : 0;
  }
  __syncthreads();
  if (lastFlag){
    __threadfence();
    float s=0.f, c=0.f;
    if (t < 256){ s = partials[2*t]; c = partials[2*t+1]; }
    #pragma unroll
    for (int off=32; off; off>>=1){ s += __shfl_xor(s,off); c += __shfl_xor(c,off); }
    if (l==0){ rs[w]=s; rc[w]=c; }
    __syncthreads();
    if (t==0){
      float S=0.f, C=0.f;
      for (int q=0;q<16;q++){ S+=rs[q]; C+=rc[q]; }
      out[0] = (C>0.0f) ? S/fmaxf(C,1.0f) : 0.0f;
    }
  }
}

// ================= fallback path (small workspace) =================
__global__ __launch_bounds__(256) void k_sq(const float* __restrict__ E, float* __restrict__ sq){
  int i = blockIdx.x*256 + threadIdx.x;
  if (i >= BN) return;
  const float4* r = (const float4*)E + (size_t)i*D4;
  float a0=0.f,a1=0.f,a2=0.f,a3=0.f;
  #pragma unroll
  for (int q=0;q<D4;q+=4){
    a0 = fma4(r[q],r[q],a0);   a1 = fma4(r[q+1],r[q+1],a1);
    a2 = fma4(r[q+2],r[q+2],a2); a3 = fma4(r[q+3],r[q+3],a3);
  }
  sq[i] = (a0+a1)+(a2+a3);
}

__global__ __launch_bounds__(256) void k_pos(const float* __restrict__ E, const int* __restrict__ labels,
                       const float* __restrict__ sq, float* __restrict__ apw,
                       int* __restrict__ hpw, int* __restrict__ anypw){
  __shared__ int members[1024];
  __shared__ float4 mem4[SCAP*65];
  __shared__ int cnts[16][4];
  __shared__ int offs[16][4];
  __shared__ int cntS;
  int t = threadIdx.x, lane = t&63, w = t>>6;
  int c = blockIdx.x >> 2, split = blockIdx.x & 3;
  for (int ch=0; ch<16; ch++){
    bool m = (labels[ch*256 + t] == c);
    unsigned long long mask = __ballot(m);
    if (lane==0) cnts[ch][w] = __popcll(mask);
  }
  __syncthreads();
  if (t==0){
    int run=0;
    for (int ch=0; ch<16; ch++)
      for (int q=0;q<4;q++){ offs[ch][q]=run; run+=cnts[ch][q]; }
    cntS = run;
  }
  __syncthreads();
  int cnt = cntS; if (cnt>1024) cnt=1024;
  for (int ch=0; ch<16; ch++){
    int idx = ch*256 + t;
    bool m = (labels[idx] == c);
    unsigned long long mask = __ballot(m);
    int my = __popcll(mask & ((1ull<<lane)-1ull));
    int pos = offs[ch][w] + my;
    if (m && pos < 1024) members[pos] = idx;
  }
  int S = (cnt < SCAP) ? cnt : SCAP;
  int anyp = (cnt >= 2) ? 1 : 0;
  __syncthreads();
  const float4* E4 = (const float4*)E;
  for (int idx=t; idx<S*64; idx+=256){
    int row = idx>>6, f = idx&63;
    mem4[row*65 + f] = E4[(size_t)members[row]*D4 + f];
  }
  __syncthreads();
  int esplit = split*4 + w;
  int p = lane&3, cand = lane>>2;
  int passes = (cnt+15)>>4;
  for (int mi=esplit; mi<cnt; mi+=16){
    int i = members[mi];
    float sqi = sq[i];
    float4 ai4[16];
    if (mi < S){
      #pragma unroll
      for (int m=0;m<16;m++) ai4[m] = mem4[mi*65 + p + 4*m];
    } else {
      #pragma unroll
      for (int m=0;m<16;m++) ai4[m] = E4[(size_t)i*D4 + p + 4*m];
    }
    float bv = -INFINITY; int bj = IMAX;
    for (int ps=0; ps<passes; ps++){
      int mj = ps*16 + cand;
      if (mj < cnt && mj != mi){
        int j = members[mj];
        float a0v=0.f, a1v=0.f;
        if (mj < S){
          const float4* rj = mem4 + mj*65 + p;
          #pragma unroll
          for (int m=0;m<16;m+=2){ a0v=fma4(ai4[m],rj[4*m],a0v); a1v=fma4(ai4[m+1],rj[4*(m+1)],a1v); }
        } else {
          const float4* rj = E4 + (size_t)j*D4 + p;
          #pragma unroll
          for (int m=0;m<16;m+=2){ a0v=fma4(ai4[m],rj[4*m],a0v); a1v=fma4(ai4[m+1],rj[4*(m+1)],a1v); }
        }
        float acc = a0v+a1v;
        acc += __shfl_xor(acc,1); acc += __shfl_xor(acc,2);
        float d = sqrtf(fmaxf(sqi + sq[j] - 2.0f*acc, 0.0f));
        if (p==0){ if (d > bv || (d==bv && j<bj)){ bv=d; bj=j; } }
      }
    }
    #pragma unroll
    for (int off=32; off; off>>=1){
      float v2=__shfl_xor(bv,off); int j2=__shfl_xor(bj,off);
      if (v2>bv || (v2==bv && j2<bj)){ bv=v2; bj=j2; }
    }
    if (lane==0){
      int J = (bj==IMAX) ? 0 : bj;
      apw[i]=bv; hpw[i]=J; anypw[i]=anyp;
    }
  }
}

__global__ __launch_bounds__(256,2) void k_main(const float* __restrict__ E, const int* __restrict__ labels,
     const float* __restrict__ sq, const float* __restrict__ apw, const int* __restrict__ hpw,
     const int* __restrict__ anypw, float* __restrict__ partials){
  __shared__ float4 At[MI*68 + 4];
  __shared__ float redv[4][MI]; __shared__ int redj[4][MI]; __shared__ int redsm[4][MI];
  __shared__ int finNeg[MI]; __shared__ int finVal[MI];
  __shared__ float redp[4], redn[4];
  int t=threadIdx.x, lane=t&63, w=t>>6;
  int a0 = blockIdx.x * MI;
  const float4* E4 = (const float4*)E;
  for (int idx=t; idx<MI*64; idx+=256){
    int a=idx>>6, q=idx&63, pp=q&3, mm=q>>2;
    At[a*68 + pp*17 + mm] = E4[(size_t)(a0+a)*D4 + q];
  }
  __syncthreads();
  float apv[MI], sqi[MI]; int labi[MI];
  #pragma unroll
  for (int a=0;a<MI;a++){ apv[a]=apw[a0+a]; sqi[a]=sq[a0+a]; labi[a]=labels[a0+a]; }
  float mnv[MI]; int mnj[MI]; int smj[MI];
  #pragma unroll
  for (int a=0;a<MI;a++){ mnv[a]=INFINITY; mnj[a]=0; smj[a]=IMAX; }
  int s = t>>2, p = t&3;
  for (int it=0; it<16; it++){
    int colb = it*256 + 4*s;
    const float4* __restrict__ bp = E4 + (size_t)colb*D4 + p;
    float acc[MI][4];
    #pragma unroll
    for (int a=0;a<MI;a++){
      #pragma unroll
      for (int c2=0;c2<4;c2++) acc[a][c2]=0.0f;
    }
    for (int mg=0; mg<4; mg++){
      float4 b[4][4];
      #pragma unroll
      for (int c2=0;c2<4;c2++){
        #pragma unroll
        for (int m=0;m<4;m++) b[m][c2] = bp[(size_t)c2*D4 + mg*16 + m*4];
      }
      #pragma unroll
      for (int a=0;a<MI;a++){
        float4 a4[4];
        #pragma unroll
        for (int m=0;m<4;m++) a4[m] = At[a*68 + p*17 + mg*4 + m];
        #pragma unroll
        for (int m=0;m<4;m++){
          #pragma unroll
          for (int c2=0;c2<4;c2++) acc[a][c2] = fma4(a4[m], b[m][c2], acc[a][c2]);
        }
      }
    }
    #pragma unroll
    for (int a=0;a<MI;a++){
      #pragma unroll
      for (int c2=0;c2<4;c2++){
        float v = acc[a][c2];
        v += __shfl_xor(v,1); v += __shfl_xor(v,2);
        acc[a][c2] = v;
      }
    }
    #pragma unroll
    for (int c2=0;c2<4;c2++){
      int j = colb + c2;
      int lj = labels[j]; float sqj = sq[j];
      #pragma unroll
      for (int a=0;a<MI;a++){
        float d = sqrtf(fmaxf(sqi[a]+sqj-2.0f*acc[a][c2], 0.0f));
        if (lj != labi[a]){
          if (d < mnv[a]){ mnv[a]=d; mnj[a]=j; }
          if (d > apv[a] && d < apv[a]+MARGINF && j < smj[a]) smj[a]=j;
        }
      }
    }
  }
  #pragma unroll
  for (int a=0;a<MI;a++){
    float v=mnv[a]; int j=mnj[a]; int sm=smj[a];
    #pragma unroll
    for (int off=32; off; off>>=1){
      float v2=__shfl_xor(v,off); int j2=__shfl_xor(j,off); int s2=__shfl_xor(sm,off);
      if (v2<v || (v2==v && j2<j)){ v=v2; j=j2; }
      sm = (s2<sm)?s2:sm;
    }
    if (lane==0){ redv[w][a]=v; redj[w][a]=j; redsm[w][a]=sm; }
  }
  __syncthreads();
  if (t < MI){
    int a=t;
    float V=INFINITY; int J=0; int S=IMAX; bool first=true;
    for (int q=0;q<4;q++){
      float v2=redv[q][a]; int j2=redj[q][a];
      if (first || v2<V || (v2==V && j2<J)){ V=v2; J=j2; first=false; }
      int s2=redsm[q][a]; S=(s2<S)?s2:S;
    }
    bool anyneg = (V < INFINITY);
    finNeg[a] = (S != IMAX) ? S : J;
    finVal[a] = (anypw[a0+a] != 0 && anyneg) ? 1 : 0;
  }
  __syncthreads();
  float lsum=0.0f, lcnt=0.0f;
  for (int a=0;a<MI;a++){
    if (finVal[a]){
      int hp = hpw[a0+a]; int ng = finNeg[a];
      float ai = E[(size_t)(a0+a)*DIM + t];
      float pv = E[(size_t)hp*DIM + t];
      float nv = E[(size_t)ng*DIM + t];
      float dp = ai - pv + EPSF; float dn = ai - nv + EPSF;
      float sp = dp*dp, sn = dn*dn;
      #pragma unroll
      for (int off=32; off; off>>=1){ sp += __shfl_xor(sp,off); sn += __shfl_xor(sn,off); }
      if (lane==0){ redp[w]=sp; redn[w]=sn; }
    }
    __syncthreads();
    if (finVal[a] && t==0){
      float SP=(redp[0]+redp[1])+(redp[2]+redp[3]);
      float SN=(redn[0]+redn[1])+(redn[2]+redn[3]);
      lsum += fmaxf(sqrtf(SP)-sqrtf(SN)+MARGINF, 0.0f);
      lcnt += 1.0f;
    }
    __syncthreads();
  }
  if (t==0){ partials[2*blockIdx.x]=lsum; partials[2*blockIdx.x+1]=lcnt; }
}

__global__ __launch_bounds__(256) void k_fin(const float* __restrict__ partials, float* __restrict__ out, int nb){
  __shared__ float rs[4], rc[4];
  int t=threadIdx.x, lane=t&63, w=t>>6;
  float s=0.f, c=0.f;
  for (int q=t;q<nb;q+=256){ s+=partials[2*q]; c+=partials[2*q+1]; }
  #pragma unroll
  for (int off=32; off; off>>=1){ s+=__shfl_xor(s,off); c+=__shfl_xor(c,off); }
  if (lane==0){ rs[w]=s; rc[w]=c; }
  __syncthreads();
  if (t==0){
    float S=(rs[0]+rs[1])+(rs[2]+rs[3]);
    float C=(rc[0]+rc[1])+(rc[2]+rc[3]);
    out[0] = (C>0.0f) ? S/fmaxf(C,1.0f) : 0.0f;
  }
}

extern "C" void kernel_launch(void* const* d_in, const int* in_sizes, int n_in,
                              void* d_out, int out_size, void* d_ws, size_t ws_size,
                              hipStream_t stream) {
  const float* E      = (const float*)d_in[0];   // 4096x256 fp32
  const int*   labels = (const int*)d_in[1];     // 4096 int32
  float* out = (float*)d_out;

  float* sqw      = (float*)d_ws;          // 4096 f
  float* apw      = sqw + BN;              // 4096 f   (fallback only)
  int*   hpw      = (int*)(apw + BN);      // 4096 i   (fallback only)
  int*   anypw    = hpw + BN;              // 4096 i   (fallback only)
  float* partials = (float*)(anypw + BN);  // 1024 f
  unsigned int* counter = (unsigned int*)(partials + 1024);
  float* ET       = (float*)((char*)d_ws + 131072);  // 4 MB, 128 KB-aligned
  bool big = ws_size >= (size_t)(131072 + 4*1024*1024);

  if (big){
    k_pre   <<<64,    256,  0, stream>>>(E, ET, sqw, counter);
    k_main_t<<<BN/MT, 1024, 0, stream>>>(E, ET, labels, sqw, partials, counter, out);
  } else {
    k_sq  <<<BN/256, 256, 0, stream>>>(E, sqw);
    k_pos <<<256,    256, 0, stream>>>(E, labels, sqw, apw, hpw, anypw);
    k_main<<<BN/MI,  256, 0, stream>>>(E, labels, sqw, apw, hpw, anypw, partials);
    k_fin <<<1,      256, 0, stream>>>(partials, out, BN/MI);
  }
}